// Round 5
// baseline (1469.234 us; speedup 1.0000x reference)
//
#include <hip/hip_runtime.h>
#include <hip/hip_bf16.h>

#define N 4096
#define IND 256
#define OUTD 128
#define NEGV -9000000000000000.0f

// ---------------- Kernel A: wh = lstm_out @ W  (4096x256 @ 256x128) ----------------
__global__ __launch_bounds__(256) void wh_kernel(const float* __restrict__ x,
                                                 const float* __restrict__ W,
                                                 float* __restrict__ wh) {
    __shared__ float xs[16][IND];
    const int t = threadIdx.x;
    const int i0 = blockIdx.x * 16;
    const float4* src = (const float4*)(x + (size_t)i0 * IND);
    float4* dst = (float4*)&xs[0][0];
    #pragma unroll
    for (int q = 0; q < 4; ++q) dst[t + q * 256] = src[t + q * 256];
    __syncthreads();
    const int c = t & 127;
    const int rh = t >> 7;
    float acc[8];
    #pragma unroll
    for (int r = 0; r < 8; ++r) acc[r] = 0.f;
    for (int k = 0; k < IND; ++k) {
        float w = W[k * OUTD + c];
        #pragma unroll
        for (int r = 0; r < 8; ++r) acc[r] = fmaf(xs[rh * 8 + r][k], w, acc[r]);
    }
    #pragma unroll
    for (int r = 0; r < 8; ++r)
        wh[(size_t)(i0 + rh * 8 + r) * OUTD + c] = acc[r];
}

// ---------------- Kernel A2: s_i = wh @ a_i, s_j = wh @ a_j ----------------
__global__ __launch_bounds__(128) void sij_kernel(const float* __restrict__ wh,
                                                  const float* __restrict__ a,
                                                  float* __restrict__ s_i,
                                                  float* __restrict__ s_j) {
    const int i = blockIdx.x;
    const int c = threadIdx.x;
    float v = wh[(size_t)i * OUTD + c];
    float p = v * a[c];              // a_i = a[0:128]
    float q = v * a[OUTD + 5 + c];   // a_j = a[133:261]
    #pragma unroll
    for (int off = 32; off >= 1; off >>= 1) {
        p += __shfl_down(p, off);
        q += __shfl_down(q, off);
    }
    __shared__ float tmp[4];
    if ((c & 63) == 0) { tmp[c >> 6] = p; tmp[2 + (c >> 6)] = q; }
    __syncthreads();
    if (c == 0) { s_i[i] = tmp[0] + tmp[1]; s_j[i] = tmp[2] + tmp[3]; }
}

// ---------------- Kernel B: fully-fused flash GAT ----------------
// Grid = 512 blocks of 512 threads (8 waves) = exactly 2 blocks/CU.
// Each block: 8 rows x full 4096 j as 8 pipelined subtiles of 512, online softmax.
// Pipeline (T14 async-stage): edge loads for subtile st+1 (40 dwords/lane, 40 VGPR)
// are ISSUED before PV(st); HBM latency hides under PV's FMA work, keeping the
// HBM pipe near-continuously busy. No partials, no merge kernel.
// launch_bounds(512,4): VGPR cap 128 for 2 blocks/CU. Round-3 lesson: tighter caps
// spill the accumulators (WRITE_SIZE balloons) — watch that counter.
#define BI 8
#define BJ 512
#define NSUB (N / BJ)     // 8
#define PSTR 528          // P row stride (16-float aligned)
#define RSTR 132          // red row stride (4-float aligned)

__global__ __launch_bounds__(512, 4) void gat_full(const float* __restrict__ edges,
                                                   const float* __restrict__ wh,
                                                   const float* __restrict__ s_iv,
                                                   const float* __restrict__ s_jv,
                                                   const float* __restrict__ a,
                                                   float* __restrict__ out) {
    __shared__ float P[BI * PSTR];   // 16.9 KB; overlaid as red[4][BI][RSTR] at the end
    __shared__ float fbuf[BI];
    __shared__ float lbuf[BI];

    const int t = threadIdx.x;
    const int i0 = blockIdx.x * BI;

    const int r = t >> 6;     // wave id == row index in block
    const int s = t & 63;
    const int i = i0 + r;

    const float ae0 = a[OUTD + 0], ae1 = a[OUTD + 1], ae2 = a[OUTD + 2],
                ae3 = a[OUTD + 3], ae4 = a[OUTD + 4];
    const float si = s_iv[i];

    const int c4 = (t & 31) * 4;
    const int js = t >> 5;           // 0..15

    float m, l;
    float4 acc[BI];
    #pragma unroll
    for (int rr = 0; rr < BI; ++rr) acc[rr] = make_float4(0.f, 0.f, 0.f, 0.f);

    // ---- subtile 0 scores (not pipelined) ----
    {
        float sc[8];
        float lmax = -1e30f;
        const float* eb = edges + ((size_t)i * N + s) * 5;
        #pragma unroll
        for (int k = 0; k < 8; ++k) {
            const float* e = eb + k * (64 * 5);
            float d = e[4] * ae4;
            d = fmaf(e[0], ae0, d);
            d = fmaf(e[1], ae1, d);
            d = fmaf(e[2], ae2, d);
            d = fmaf(e[3], ae3, d);
            const int j = s + k * 64;
            float v = si + d + s_jv[j];
            v = fmaxf(v, 0.2f * v);       // leaky relu (before mask, matches ref)
            if (j == i) v = NEGV;
            sc[k] = v;
            lmax = fmaxf(lmax, v);
        }
        #pragma unroll
        for (int off = 32; off >= 1; off >>= 1)
            lmax = fmaxf(lmax, __shfl_xor(lmax, off));
        m = lmax;
        float lsum = 0.f;
        #pragma unroll
        for (int k = 0; k < 8; ++k) {
            const float p = __expf(sc[k] - m);
            P[r * PSTR + s + k * 64] = p;
            lsum += p;
        }
        #pragma unroll
        for (int off = 32; off >= 1; off >>= 1)
            lsum += __shfl_xor(lsum, off);
        l = lsum;
    }
    __syncthreads();

    for (int st = 0; st < NSUB; ++st) {
        // ---- issue prefetch of subtile st+1 edges (hides under PV below) ----
        float e1[8][5];
        const int jn = (st + 1) * BJ;
        if (st + 1 < NSUB) {
            const float* eb = edges + ((size_t)i * N + (size_t)(jn + s)) * 5;
            #pragma unroll
            for (int k = 0; k < 8; ++k) {
                #pragma unroll
                for (int q = 0; q < 5; ++q)
                    e1[k][q] = eb[k * (64 * 5) + q];
            }
        }

        // ---- rescale acc by this subtile's f (computed with its scores) ----
        if (st > 0) {
            #pragma unroll
            for (int rr = 0; rr < BI; ++rr) {
                const float fr = fbuf[rr];
                acc[rr].x *= fr; acc[rr].y *= fr; acc[rr].z *= fr; acc[rr].w *= fr;
            }
        }

        // ---- PV over subtile st ----
        {
            const int j0 = st * BJ;
            const float* whp = wh + (size_t)(j0 + js * 32) * OUTD + c4;
            const int pb = js * 32;
            for (int jj = 0; jj < 32; jj += 4) {
                const float4 w0 = *(const float4*)(whp + (jj + 0) * OUTD);
                const float4 w1 = *(const float4*)(whp + (jj + 1) * OUTD);
                const float4 w2 = *(const float4*)(whp + (jj + 2) * OUTD);
                const float4 w3 = *(const float4*)(whp + (jj + 3) * OUTD);
                #pragma unroll
                for (int rr = 0; rr < BI; ++rr) {
                    const float4 p = *(const float4*)&P[rr * PSTR + pb + jj];
                    acc[rr].x = fmaf(p.x, w0.x, acc[rr].x);
                    acc[rr].y = fmaf(p.x, w0.y, acc[rr].y);
                    acc[rr].z = fmaf(p.x, w0.z, acc[rr].z);
                    acc[rr].w = fmaf(p.x, w0.w, acc[rr].w);
                    acc[rr].x = fmaf(p.y, w1.x, acc[rr].x);
                    acc[rr].y = fmaf(p.y, w1.y, acc[rr].y);
                    acc[rr].z = fmaf(p.y, w1.z, acc[rr].z);
                    acc[rr].w = fmaf(p.y, w1.w, acc[rr].w);
                    acc[rr].x = fmaf(p.z, w2.x, acc[rr].x);
                    acc[rr].y = fmaf(p.z, w2.y, acc[rr].y);
                    acc[rr].z = fmaf(p.z, w2.z, acc[rr].z);
                    acc[rr].w = fmaf(p.z, w2.w, acc[rr].w);
                    acc[rr].x = fmaf(p.w, w3.x, acc[rr].x);
                    acc[rr].y = fmaf(p.w, w3.y, acc[rr].y);
                    acc[rr].z = fmaf(p.w, w3.z, acc[rr].z);
                    acc[rr].w = fmaf(p.w, w3.w, acc[rr].w);
                }
            }
        }
        __syncthreads();   // all P reads done

        // ---- scores for subtile st+1 from prefetched registers ----
        if (st + 1 < NSUB) {
            float sc[8];
            float lmax = -1e30f;
            #pragma unroll
            for (int k = 0; k < 8; ++k) {
                float d = e1[k][4] * ae4;
                d = fmaf(e1[k][0], ae0, d);
                d = fmaf(e1[k][1], ae1, d);
                d = fmaf(e1[k][2], ae2, d);
                d = fmaf(e1[k][3], ae3, d);
                const int j = jn + s + k * 64;
                float v = si + d + s_jv[j];
                v = fmaxf(v, 0.2f * v);
                if (j == i) v = NEGV;
                sc[k] = v;
                lmax = fmaxf(lmax, v);
            }
            #pragma unroll
            for (int off = 32; off >= 1; off >>= 1)
                lmax = fmaxf(lmax, __shfl_xor(lmax, off));
            const float newm = fmaxf(m, lmax);
            const float f = __expf(m - newm);
            m = newm;
            float lsum = 0.f;
            #pragma unroll
            for (int k = 0; k < 8; ++k) {
                const float p = __expf(sc[k] - m);
                P[r * PSTR + s + k * 64] = p;
                lsum += p;
            }
            #pragma unroll
            for (int off = 32; off >= 1; off >>= 1)
                lsum += __shfl_xor(lsum, off);
            l = l * f + lsum;
            if (s == 0) fbuf[r] = f;
            __syncthreads();   // P + fbuf ready for next PV
        }
    }

    // ---- finalize: fold js-pairs, tree-reduce 8 waves, divide by l, store ----
    if (s == 0) lbuf[r] = l;
    #pragma unroll
    for (int rr = 0; rr < BI; ++rr) {
        acc[rr].x += __shfl_xor(acc[rr].x, 32);
        acc[rr].y += __shfl_xor(acc[rr].y, 32);
        acc[rr].z += __shfl_xor(acc[rr].z, 32);
        acc[rr].w += __shfl_xor(acc[rr].w, 32);
    }
    __syncthreads();   // P reads done (already), lbuf visible; safe to overlay red

    float* red = P;
    const bool lo = (s < 32);
    if (r >= 4 && lo) {
        #pragma unroll
        for (int rr = 0; rr < BI; ++rr)
            *(float4*)&red[((r - 4) * BI + rr) * RSTR + c4] = acc[rr];
    }
    __syncthreads();
    if (r < 4 && lo) {
        #pragma unroll
        for (int rr = 0; rr < BI; ++rr) {
            const float4 v = *(const float4*)&red[(r * BI + rr) * RSTR + c4];
            acc[rr].x += v.x; acc[rr].y += v.y; acc[rr].z += v.z; acc[rr].w += v.w;
        }
    }
    __syncthreads();
    if (r >= 2 && r < 4 && lo) {
        #pragma unroll
        for (int rr = 0; rr < BI; ++rr)
            *(float4*)&red[((r - 2) * BI + rr) * RSTR + c4] = acc[rr];
    }
    __syncthreads();
    if (r < 2 && lo) {
        #pragma unroll
        for (int rr = 0; rr < BI; ++rr) {
            const float4 v = *(const float4*)&red[(r * BI + rr) * RSTR + c4];
            acc[rr].x += v.x; acc[rr].y += v.y; acc[rr].z += v.z; acc[rr].w += v.w;
        }
    }
    __syncthreads();
    if (r == 1 && lo) {
        #pragma unroll
        for (int rr = 0; rr < BI; ++rr)
            *(float4*)&red[rr * RSTR + c4] = acc[rr];
    }
    __syncthreads();
    if (r == 0 && lo) {
        #pragma unroll
        for (int rr = 0; rr < BI; ++rr) {
            const float4 v = *(const float4*)&red[rr * RSTR + c4];
            const float rl = 1.0f / lbuf[rr];
            float4 o;
            o.x = (acc[rr].x + v.x) * rl;
            o.y = (acc[rr].y + v.y) * rl;
            o.z = (acc[rr].z + v.z) * rl;
            o.w = (acc[rr].w + v.w) * rl;
            *(float4*)&out[(size_t)(i0 + rr) * OUTD + c4] = o;
        }
    }
}

extern "C" void kernel_launch(void* const* d_in, const int* in_sizes, int n_in,
                              void* d_out, int out_size, void* d_ws, size_t ws_size,
                              hipStream_t stream) {
    // inputs: 0=ids(int, unused), 1=lstm_out, 2=edges_list, 3=W, 4=a, 5=first(unused)
    const float* lstm_out = (const float*)d_in[1];
    const float* edges    = (const float*)d_in[2];
    const float* W        = (const float*)d_in[3];
    const float* a        = (const float*)d_in[4];
    float* out = (float*)d_out;

    float* wh  = (float*)d_ws;                  // 4096*128
    float* s_i = wh + (size_t)N * OUTD;         // 4096
    float* s_j = s_i + N;                       // 4096

    wh_kernel<<<N / 16, 256, 0, stream>>>(lstm_out, W, wh);
    sij_kernel<<<N, 128, 0, stream>>>(wh, a, s_i, s_j);
    gat_full<<<N / BI, 512, 0, stream>>>(edges, wh, s_i, s_j, a, out);
}

// Round 6
// 248.230 us; speedup vs baseline: 5.9188x; 5.9188x over previous
//
#include <hip/hip_runtime.h>
#include <hip/hip_bf16.h>

#define N 4096
#define IND 256
#define OUTD 128
#define NEGV -9000000000000000.0f

// ---------------- Kernel A: wh = lstm_out @ W  (4096x256 @ 256x128) ----------------
// 512 blocks x 256 threads, 8 rows/block (2 blocks/CU). b128 LDS reads.
__global__ __launch_bounds__(256) void wh_kernel(const float* __restrict__ x,
                                                 const float* __restrict__ W,
                                                 float* __restrict__ wh) {
    __shared__ float xs[8][IND];
    const int t = threadIdx.x;
    const int i0 = blockIdx.x * 8;
    const float4* src = (const float4*)(x + (size_t)i0 * IND);
    float4* dst = (float4*)&xs[0][0];
    dst[t] = src[t];
    dst[t + 256] = src[t + 256];
    __syncthreads();
    const int c = t & 127;
    const int rbase = (t >> 7) * 4;
    float acc[4] = {0.f, 0.f, 0.f, 0.f};
    #pragma unroll 4
    for (int k = 0; k < IND; k += 4) {
        const float w0 = W[(k + 0) * OUTD + c];
        const float w1 = W[(k + 1) * OUTD + c];
        const float w2 = W[(k + 2) * OUTD + c];
        const float w3 = W[(k + 3) * OUTD + c];
        #pragma unroll
        for (int r = 0; r < 4; ++r) {
            const float4 xv = *(const float4*)&xs[rbase + r][k];
            acc[r] = fmaf(xv.x, w0, acc[r]);
            acc[r] = fmaf(xv.y, w1, acc[r]);
            acc[r] = fmaf(xv.z, w2, acc[r]);
            acc[r] = fmaf(xv.w, w3, acc[r]);
        }
    }
    #pragma unroll
    for (int r = 0; r < 4; ++r)
        wh[(size_t)(i0 + rbase + r) * OUTD + c] = acc[r];
}

// ---------------- Kernel A2: s_i = wh @ a_i, s_j = wh @ a_j ----------------
__global__ __launch_bounds__(128) void sij_kernel(const float* __restrict__ wh,
                                                  const float* __restrict__ a,
                                                  float* __restrict__ s_i,
                                                  float* __restrict__ s_j) {
    const int i = blockIdx.x;
    const int c = threadIdx.x;
    float v = wh[(size_t)i * OUTD + c];
    float p = v * a[c];              // a_i = a[0:128]
    float q = v * a[OUTD + 5 + c];   // a_j = a[133:261]
    #pragma unroll
    for (int off = 32; off >= 1; off >>= 1) {
        p += __shfl_down(p, off);
        q += __shfl_down(q, off);
    }
    __shared__ float tmp[4];
    if ((c & 63) == 0) { tmp[c >> 6] = p; tmp[2 + (c >> 6)] = q; }
    __syncthreads();
    if (c == 0) { s_i[i] = tmp[0] + tmp[1]; s_j[i] = tmp[2] + tmp[3]; }
}

// ---------------- Kernel B: flash GAT, 1 barrier/subtile, register prefetch ----------------
// 512 blocks x 256 threads (4 waves), BI=8 rows, BJ=128, 32 subtiles.
// Wave w owns rows 2w,2w+1 end-to-end: scores + softmax state (m,l) stay in-wave.
// Per subtile: [prefetch st+1 edges -> 20 regs] [scores(st) from regs -> P[st&1]]
// [lgkmcnt(0)+s_barrier (NO vmcnt drain -> prefetch stays in flight)] [PV(st)].
// P/fbuf double-buffered => writes(st+1) never race reads(st) with one barrier.
// launch_bounds(256,2): cap = 256 VGPR under BOTH "waves/EU" and "blocks/CU"
// readings of the 2nd arg (rounds 3/5 showed we can't trust one reading).
// PV: 16 col-groups x 8 cols (C=8), js = t>>4 j-slice; P reads are 16-lane
// broadcasts at distinct bank quads (js*8 words apart) -> conflict-free.
#define BI 8
#define BJ 128
#define NSUB (N / BJ)     // 32
#define PSTR 132

#define FMA4(A, pv, wv)                  \
    A.x = fmaf(pv, wv.x, A.x);           \
    A.y = fmaf(pv, wv.y, A.y);           \
    A.z = fmaf(pv, wv.z, A.z);           \
    A.w = fmaf(pv, wv.w, A.w);

__global__ __launch_bounds__(256, 2) void gat_flash(const float* __restrict__ edges,
                                                    const float* __restrict__ wh,
                                                    const float* __restrict__ s_iv,
                                                    const float* __restrict__ s_jv,
                                                    const float* __restrict__ a,
                                                    float* __restrict__ out) {
    __shared__ float P[2][BI][PSTR];     // 8.4 KB
    __shared__ float red[4][BI][PSTR];   // 16.9 KB (epilogue only)
    __shared__ float fbuf[2][BI];
    __shared__ float lbuf[BI];

    const int t = threadIdx.x;
    const int i0 = blockIdx.x * BI;
    const int w = t >> 6;
    const int s = t & 63;
    const int r0 = 2 * w, r1 = 2 * w + 1;

    const float ae0 = a[OUTD + 0], ae1 = a[OUTD + 1], ae2 = a[OUTD + 2],
                ae3 = a[OUTD + 3], ae4 = a[OUTD + 4];
    const float si0 = s_iv[i0 + r0];
    const float si1 = s_iv[i0 + r1];

    const int cg = t & 15;   // col group -> cols c8..c8+7
    const int c8 = cg * 8;
    const int js = t >> 4;   // j slice 0..15 (8 j each)

    float m0 = -1e30f, m1 = -1e30f, l0 = 0.f, l1 = 0.f;
    float4 acc[BI][2];
    #pragma unroll
    for (int rr = 0; rr < BI; ++rr) {
        acc[rr][0] = make_float4(0.f, 0.f, 0.f, 0.f);
        acc[rr][1] = make_float4(0.f, 0.f, 0.f, 0.f);
    }

    // prologue: load subtile-0 edges into registers
    float ecur[4][5];
    {
        const float* b0 = edges + ((size_t)(i0 + r0) * N + s) * 5;
        const float* b1 = edges + ((size_t)(i0 + r1) * N + s) * 5;
        #pragma unroll
        for (int q = 0; q < 5; ++q) {
            ecur[0][q] = b0[q];
            ecur[1][q] = b0[320 + q];   // +64 j
            ecur[2][q] = b1[q];
            ecur[3][q] = b1[320 + q];
        }
    }

    for (int st = 0; st < NSUB; ++st) {
        const int b = st & 1;
        const int jb = st * BJ;
        const bool pf = (st + 1 < NSUB);

        // ---- issue prefetch of subtile st+1 (completes during PV below) ----
        float enx[4][5];
        if (pf) {
            const float* b0 = edges + ((size_t)(i0 + r0) * N + (jb + BJ) + s) * 5;
            const float* b1 = edges + ((size_t)(i0 + r1) * N + (jb + BJ) + s) * 5;
            #pragma unroll
            for (int q = 0; q < 5; ++q) {
                enx[0][q] = b0[q];
                enx[1][q] = b0[320 + q];
                enx[2][q] = b1[q];
                enx[3][q] = b1[320 + q];
            }
        }

        // ---- scores(st) from registers ----
        const float sjA = s_jv[jb + s];
        const float sjB = s_jv[jb + 64 + s];
        float sc[4];
        #pragma unroll
        for (int cc = 0; cc < 4; ++cc) {
            float d = ecur[cc][4] * ae4;
            d = fmaf(ecur[cc][0], ae0, d);
            d = fmaf(ecur[cc][1], ae1, d);
            d = fmaf(ecur[cc][2], ae2, d);
            d = fmaf(ecur[cc][3], ae3, d);
            const float siv = (cc < 2) ? si0 : si1;
            const float sj  = (cc & 1) ? sjB : sjA;
            float v = siv + d + sj;
            v = fmaxf(v, 0.2f * v);                       // leaky relu before mask
            const int j = jb + ((cc & 1) ? 64 : 0) + s;
            const int irow = i0 + ((cc < 2) ? r0 : r1);
            if (j == irow) v = NEGV;                      // diagonal mask
            sc[cc] = v;
        }
        float mx0 = fmaxf(sc[0], sc[1]);
        float mx1 = fmaxf(sc[2], sc[3]);
        #pragma unroll
        for (int off = 32; off >= 1; off >>= 1) {
            mx0 = fmaxf(mx0, __shfl_xor(mx0, off));
            mx1 = fmaxf(mx1, __shfl_xor(mx1, off));
        }
        const float nm0 = fmaxf(m0, mx0);
        const float nm1 = fmaxf(m1, mx1);
        const float f0 = __expf(m0 - nm0);
        const float f1 = __expf(m1 - nm1);
        m0 = nm0; m1 = nm1;
        const float p0a = __expf(sc[0] - m0);
        const float p0b = __expf(sc[1] - m0);
        const float p1a = __expf(sc[2] - m1);
        const float p1b = __expf(sc[3] - m1);
        P[b][r0][s] = p0a;
        P[b][r0][64 + s] = p0b;
        P[b][r1][s] = p1a;
        P[b][r1][64 + s] = p1b;
        float ls0 = p0a + p0b;
        float ls1 = p1a + p1b;
        #pragma unroll
        for (int off = 32; off >= 1; off >>= 1) {
            ls0 += __shfl_xor(ls0, off);
            ls1 += __shfl_xor(ls1, off);
        }
        l0 = l0 * f0 + ls0;
        l1 = l1 * f1 + ls1;
        if (s == 0) { fbuf[b][r0] = f0; fbuf[b][r1] = f1; }

        // ---- barrier: drain LDS only; edge prefetch stays in flight ----
        asm volatile("s_waitcnt lgkmcnt(0)" ::: "memory");
        __builtin_amdgcn_s_barrier();
        asm volatile("" ::: "memory");

        // ---- PV(st): 8 cols/thread ----
        #pragma unroll
        for (int rr = 0; rr < BI; ++rr) {
            const float f = fbuf[b][rr];
            acc[rr][0].x *= f; acc[rr][0].y *= f; acc[rr][0].z *= f; acc[rr][0].w *= f;
            acc[rr][1].x *= f; acc[rr][1].y *= f; acc[rr][1].z *= f; acc[rr][1].w *= f;
        }
        const float* whp = wh + (size_t)(jb + js * 8) * OUTD + c8;
        #pragma unroll
        for (int jq = 0; jq < 2; ++jq) {
            float4 wa[4], wb[4];
            #pragma unroll
            for (int jj = 0; jj < 4; ++jj) {
                wa[jj] = *(const float4*)(whp + (size_t)(jq * 4 + jj) * OUTD);
                wb[jj] = *(const float4*)(whp + (size_t)(jq * 4 + jj) * OUTD + 4);
            }
            #pragma unroll
            for (int rr = 0; rr < BI; ++rr) {
                const float4 p = *(const float4*)&P[b][rr][js * 8 + jq * 4];
                FMA4(acc[rr][0], p.x, wa[0]);
                FMA4(acc[rr][1], p.x, wb[0]);
                FMA4(acc[rr][0], p.y, wa[1]);
                FMA4(acc[rr][1], p.y, wb[1]);
                FMA4(acc[rr][0], p.z, wa[2]);
                FMA4(acc[rr][1], p.z, wb[2]);
                FMA4(acc[rr][0], p.w, wa[3]);
                FMA4(acc[rr][1], p.w, wb[3]);
            }
        }

        // ---- rotate prefetch ----
        if (pf) {
            #pragma unroll
            for (int cc = 0; cc < 4; ++cc) {
                #pragma unroll
                for (int q = 0; q < 5; ++q) ecur[cc][q] = enx[cc][q];
            }
        }
    }

    // ---- epilogue ----
    if (s == 0) { lbuf[r0] = 1.0f / l0; lbuf[r1] = 1.0f / l1; }
    // fold the wave's 4 j-slices (lanes s, s^16, s^32, s^48 share a col-group)
    #pragma unroll
    for (int rr = 0; rr < BI; ++rr) {
        #pragma unroll
        for (int h = 0; h < 2; ++h) {
            acc[rr][h].x += __shfl_xor(acc[rr][h].x, 16);
            acc[rr][h].y += __shfl_xor(acc[rr][h].y, 16);
            acc[rr][h].z += __shfl_xor(acc[rr][h].z, 16);
            acc[rr][h].w += __shfl_xor(acc[rr][h].w, 16);
            acc[rr][h].x += __shfl_xor(acc[rr][h].x, 32);
            acc[rr][h].y += __shfl_xor(acc[rr][h].y, 32);
            acc[rr][h].z += __shfl_xor(acc[rr][h].z, 32);
            acc[rr][h].w += __shfl_xor(acc[rr][h].w, 32);
        }
    }
    if (s < 16) {
        #pragma unroll
        for (int rr = 0; rr < BI; ++rr) {
            *(float4*)&red[w][rr][c8] = acc[rr][0];
            *(float4*)&red[w][rr][c8 + 4] = acc[rr][1];
        }
    }
    __syncthreads();
    {
        const int rr = t >> 5;
        const int c4 = (t & 31) * 4;
        const float4 v0 = *(const float4*)&red[0][rr][c4];
        const float4 v1 = *(const float4*)&red[1][rr][c4];
        const float4 v2 = *(const float4*)&red[2][rr][c4];
        const float4 v3 = *(const float4*)&red[3][rr][c4];
        const float li = lbuf[rr];
        float4 o;
        o.x = (v0.x + v1.x + v2.x + v3.x) * li;
        o.y = (v0.y + v1.y + v2.y + v3.y) * li;
        o.z = (v0.z + v1.z + v2.z + v3.z) * li;
        o.w = (v0.w + v1.w + v2.w + v3.w) * li;
        *(float4*)&out[(size_t)(i0 + rr) * OUTD + c4] = o;
    }
}

extern "C" void kernel_launch(void* const* d_in, const int* in_sizes, int n_in,
                              void* d_out, int out_size, void* d_ws, size_t ws_size,
                              hipStream_t stream) {
    // inputs: 0=ids(int, unused), 1=lstm_out, 2=edges_list, 3=W, 4=a, 5=first(unused)
    const float* lstm_out = (const float*)d_in[1];
    const float* edges    = (const float*)d_in[2];
    const float* W        = (const float*)d_in[3];
    const float* a        = (const float*)d_in[4];
    float* out = (float*)d_out;

    float* wh  = (float*)d_ws;                  // 4096*128 f32 = 2 MB
    float* s_i = wh + (size_t)N * OUTD;         // 4096
    float* s_j = s_i + N;                       // 4096

    wh_kernel<<<N / 8, 256, 0, stream>>>(lstm_out, W, wh);
    sij_kernel<<<N, 128, 0, stream>>>(wh, a, s_i, s_j);
    gat_flash<<<N / BI, 256, 0, stream>>>(edges, wh, s_i, s_j, a, out);
}